// Round 1
// baseline (50.856 us; speedup 1.0000x reference)
//
#include <hip/hip_runtime.h>

// Problem constants (from reference): B=8, N=64, I=128, H=1024
#define BB 8
#define NN 64
#define II 128
#define HH 1024
#define TOTAL_OUT (BB * NN * II)   // 65536

// Kernel 1: v[b][j] = sum_k W[j][k] * hidden[b][k]
// One wave per j (1024 waves). W row read coalesced via float4; hidden is
// 32 KB, L2-hot broadcast-ish read.
__global__ void compute_v_kernel(const float* __restrict__ W,
                                 const float* __restrict__ hidden,
                                 float* __restrict__ v) {
    int wave = (blockIdx.x * blockDim.x + threadIdx.x) >> 6;
    int lane = threadIdx.x & 63;
    if (wave >= HH) return;
    int j = wave;

    const float4* Wrow = reinterpret_cast<const float4*>(W + (size_t)j * HH);
    const float4* Hv   = reinterpret_cast<const float4*>(hidden);

    float acc[BB];
#pragma unroll
    for (int b = 0; b < BB; ++b) acc[b] = 0.f;

#pragma unroll
    for (int it = 0; it < HH / 256; ++it) {        // 4 iterations
        float4 w4 = Wrow[it * 64 + lane];
#pragma unroll
        for (int b = 0; b < BB; ++b) {
            float4 h4 = Hv[b * (HH / 4) + it * 64 + lane];
            acc[b] += w4.x * h4.x + w4.y * h4.y + w4.z * h4.z + w4.w * h4.w;
        }
    }

#pragma unroll
    for (int b = 0; b < BB; ++b) {
        float a = acc[b];
#pragma unroll
        for (int off = 32; off > 0; off >>= 1) a += __shfl_xor(a, off, 64);
        if (lane == 0) v[b * HH + j] = a;
    }
}

// Kernel 2: out[o] = dot(enc[o, :], v[b, :]) + bias,  o = (b,n,i) flattened.
// One wave per output row: 1024 floats = 4 x float4 per lane, fully coalesced.
__global__ void bilinear_out_kernel(const float* __restrict__ enc,
                                    const float* __restrict__ v,
                                    const float* __restrict__ bias,
                                    float* __restrict__ out) {
    int wave = (blockIdx.x * blockDim.x + threadIdx.x) >> 6;
    int lane = threadIdx.x & 63;
    if (wave >= TOTAL_OUT) return;
    int o = wave;
    int b = o >> 13;                               // N*I = 8192 = 2^13

    const float4* erow = reinterpret_cast<const float4*>(enc) + (size_t)o * (HH / 4);
    const float4* vrow = reinterpret_cast<const float4*>(v)   + (size_t)b * (HH / 4);

    float acc = 0.f;
#pragma unroll
    for (int it = 0; it < HH / 256; ++it) {        // 4 iterations
        float4 e4 = erow[it * 64 + lane];
        float4 v4 = vrow[it * 64 + lane];
        acc += e4.x * v4.x + e4.y * v4.y + e4.z * v4.z + e4.w * v4.w;
    }

#pragma unroll
    for (int off = 32; off > 0; off >>= 1) acc += __shfl_xor(acc, off, 64);
    if (lane == 0) out[o] = acc + bias[0];
}

extern "C" void kernel_launch(void* const* d_in, const int* in_sizes, int n_in,
                              void* d_out, int out_size, void* d_ws, size_t ws_size,
                              hipStream_t stream) {
    const float* hidden = (const float*)d_in[0];   // [B, H]
    const float* enc    = (const float*)d_in[1];   // [B, N, I, H]
    // d_in[2] = input_lengths (unused by the math)
    const float* W      = (const float*)d_in[3];   // [H, H]
    const float* bias   = (const float*)d_in[4];   // [1]
    float* out = (float*)d_out;                    // [B, N, I] f32
    float* v   = (float*)d_ws;                     // [B, H] scratch = 32 KB

    // Kernel 1: 1024 waves -> 256 blocks x 256 threads
    compute_v_kernel<<<(HH * 64) / 256, 256, 0, stream>>>(W, hidden, v);

    // Kernel 2: 65536 waves -> 16384 blocks x 256 threads
    bilinear_out_kernel<<<(TOTAL_OUT * 64) / 256, 256, 0, stream>>>(enc, v, bias, out);
}

// Round 2
// 50.566 us; speedup vs baseline: 1.0057x; 1.0057x over previous
//
#include <hip/hip_runtime.h>

// Problem constants (from reference): B=8, N=64, I=128, H=1024
#define BB 8
#define NN 64
#define II 128
#define HH 1024
#define TOTAL_OUT (BB * NN * II)   // 65536

// Kernel 1: v[b][j] = sum_k W[j][k] * hidden[b][k]
// One wave per j (1024 waves). W row read coalesced via float4; hidden is
// 32 KB, L2-hot.
__global__ void compute_v_kernel(const float* __restrict__ W,
                                 const float* __restrict__ hidden,
                                 float* __restrict__ v) {
    int wave = (blockIdx.x * blockDim.x + threadIdx.x) >> 6;
    int lane = threadIdx.x & 63;
    if (wave >= HH) return;
    int j = wave;

    const float4* Wrow = reinterpret_cast<const float4*>(W + (size_t)j * HH);
    const float4* Hv   = reinterpret_cast<const float4*>(hidden);

    float acc[BB];
#pragma unroll
    for (int b = 0; b < BB; ++b) acc[b] = 0.f;

#pragma unroll
    for (int it = 0; it < HH / 256; ++it) {        // 4 iterations
        float4 w4 = Wrow[it * 64 + lane];
#pragma unroll
        for (int b = 0; b < BB; ++b) {
            float4 h4 = Hv[b * (HH / 4) + it * 64 + lane];
            acc[b] += w4.x * h4.x + w4.y * h4.y + w4.z * h4.z + w4.w * h4.w;
        }
    }

#pragma unroll
    for (int b = 0; b < BB; ++b) {
        float a = acc[b];
#pragma unroll
        for (int off = 32; off > 0; off >>= 1) a += __shfl_xor(a, off, 64);
        if (lane == 0) v[b * HH + j] = a;
    }
}

// Kernel 2: out[o] = dot(enc[o, :], v[b, :]) + bias.
// One wave per TWO consecutive output rows: 8 independent erow float4 loads
// in flight per iteration, v row loaded once for both rows (L2-hit),
// half the waves / reductions / dispatch packets vs one-row-per-wave.
__global__ void bilinear_out_kernel(const float* __restrict__ enc,
                                    const float* __restrict__ v,
                                    const float* __restrict__ bias,
                                    float* __restrict__ out) {
    int wave = (blockIdx.x * blockDim.x + threadIdx.x) >> 6;
    int lane = threadIdx.x & 63;
    int o0 = wave * 2;
    if (o0 >= TOTAL_OUT) return;
    int b = o0 >> 13;                               // N*I = 8192 = 2^13
    // o0 even and 8192 rows per b (even) -> o0 and o0+1 share the same b.

    const float4* e0 = reinterpret_cast<const float4*>(enc) + (size_t)o0 * (HH / 4);
    const float4* e1 = e0 + (HH / 4);
    const float4* vr = reinterpret_cast<const float4*>(v) + (size_t)b * (HH / 4);

    float a0 = 0.f, a1 = 0.f;
#pragma unroll
    for (int it = 0; it < HH / 256; ++it) {         // 4 iterations
        float4 x0 = e0[it * 64 + lane];
        float4 x1 = e1[it * 64 + lane];
        float4 vv = vr[it * 64 + lane];
        a0 += x0.x * vv.x + x0.y * vv.y + x0.z * vv.z + x0.w * vv.w;
        a1 += x1.x * vv.x + x1.y * vv.y + x1.z * vv.z + x1.w * vv.w;
    }

#pragma unroll
    for (int off = 32; off > 0; off >>= 1) {
        a0 += __shfl_xor(a0, off, 64);
        a1 += __shfl_xor(a1, off, 64);
    }
    if (lane == 0) {
        float bb = bias[0];
        out[o0]     = a0 + bb;
        out[o0 + 1] = a1 + bb;
    }
}

extern "C" void kernel_launch(void* const* d_in, const int* in_sizes, int n_in,
                              void* d_out, int out_size, void* d_ws, size_t ws_size,
                              hipStream_t stream) {
    const float* hidden = (const float*)d_in[0];   // [B, H]
    const float* enc    = (const float*)d_in[1];   // [B, N, I, H]
    // d_in[2] = input_lengths (unused by the math)
    const float* W      = (const float*)d_in[3];   // [H, H]
    const float* bias   = (const float*)d_in[4];   // [1]
    float* out = (float*)d_out;                    // [B, N, I] f32
    float* v   = (float*)d_ws;                     // [B, H] scratch = 32 KB

    // Kernel 1: 1024 waves -> 256 blocks x 256 threads
    compute_v_kernel<<<(HH * 64) / 256, 256, 0, stream>>>(W, hidden, v);

    // Kernel 2: 32768 waves (2 rows each) -> 8192 blocks x 256 threads
    bilinear_out_kernel<<<(TOTAL_OUT / 2 * 64) / 256, 256, 0, stream>>>(enc, v, bias, out);
}